// Round 6
// baseline (319.261 us; speedup 1.0000x reference)
//
#include <hip/hip_runtime.h>
#include <math.h>

// Problem constants (reference: N=20000, E=160000, F=128, H=4, C1=128, C2=256, G=64, NCLS=10)
#define FDIM 128
#define HEADS 4
#define C1DIM 128
#define C2DIM 256
#define NGRAPH 64
#define NCLS 10
#define PCHUNK 8

typedef __attribute__((ext_vector_type(8))) short short8;   // 8 bf16 (4 VGPRs)
typedef __attribute__((ext_vector_type(4))) float float4v;  // 4 fp32 acc

__device__ __forceinline__ unsigned short f2bf(float f) {
    unsigned u = __builtin_bit_cast(unsigned, f);
    unsigned r = (u + 0x7FFFu + ((u >> 16) & 1u)) >> 16;   // RNE
    return (unsigned short)r;
}
__device__ __forceinline__ float bflo(int u) { return __builtin_bit_cast(float, (unsigned)u << 16); }
__device__ __forceinline__ float bfhi(int u) { return __builtin_bit_cast(float, (unsigned)u & 0xffff0000u); }
__device__ __forceinline__ float lrelu(float x) { return x > 0.f ? x : 0.2f * x; }

// ---------------- CSR build ----------------
__global__ void hist_kernel(const int* __restrict__ ei, int E, int* __restrict__ counts) {
    int i = blockIdx.x * blockDim.x + threadIdx.x;
    if (i >= 2 * E) return;
    int dst = (i < E) ? ei[E + i] : ei[i - E];
    atomicAdd(&counts[dst], 1);
}

__global__ __launch_bounds__(1024) void scan_kernel(int* __restrict__ counts_cursor,
                                                    int* __restrict__ ofs, int N) {
    __shared__ int part[1024];
    int t = threadIdx.x;
    int chunk = (N + 1023) / 1024;
    int b = t * chunk;
    int e = b + chunk; if (e > N) e = N;
    int s = 0;
    for (int i = b; i < e; ++i) s += counts_cursor[i];
    part[t] = s;
    __syncthreads();
    for (int o = 1; o < 1024; o <<= 1) {
        int v = (t >= o) ? part[t - o] : 0;
        __syncthreads();
        part[t] += v;
        __syncthreads();
    }
    int run = part[t] - s;
    for (int i = b; i < e; ++i) {
        int c = counts_cursor[i];
        ofs[i] = run;
        counts_cursor[i] = run;
        run += c;
    }
    if (t == 1023) ofs[N] = part[1023];
}

__global__ void scatter_kernel(const int* __restrict__ ei, int E,
                               int* __restrict__ cursor, int* __restrict__ esrc,
                               int* __restrict__ edst) {
    int i = blockIdx.x * blockDim.x + threadIdx.x;
    if (i >= 2 * E) return;
    int src = ei[i];
    int dst = (i < E) ? ei[E + i] : ei[i - E];
    int pos = atomicAdd(&cursor[dst], 1);
    esrc[pos] = src;
    edst[pos] = dst;
}

// ---------------- fp32 -> bf16 conversions ----------------
__global__ void cvt_kernel(const float* __restrict__ src, unsigned short* __restrict__ dst, int n4) {
    int i = blockIdx.x * blockDim.x + threadIdx.x;
    if (i >= n4) return;
    float4 v = ((const float4*)src)[i];
    ushort4 o;
    o.x = f2bf(v.x); o.y = f2bf(v.y); o.z = f2bf(v.z); o.w = f2bf(v.w);
    ((ushort4*)dst)[i] = o;
}

// Transpose-convert weights: W[K,N] fp32 -> Wt[N,K] bf16. Grid (N/32, K/32), block (32,8).
__global__ void tconv_kernel(const float* __restrict__ W, unsigned short* __restrict__ Wt,
                             int K, int N_) {
    __shared__ float tile[32][33];
    int bx = blockIdx.x * 32;
    int by = blockIdx.y * 32;
    int tx = threadIdx.x, ty = threadIdx.y;
    #pragma unroll
    for (int r = 0; r < 32; r += 8)
        tile[ty + r][tx] = W[(size_t)(by + ty + r) * N_ + bx + tx];
    __syncthreads();
    #pragma unroll
    for (int r = 0; r < 32; r += 8)
        Wt[(size_t)(bx + ty + r) * K + by + tx] = f2bf(tile[tx][ty + r]);
}

// ---------------- bf16 MFMA GEMM: C[M,N] = A[M,K] @ Bt[N,K]^T, bf16 out ----------------
__global__ __launch_bounds__(256) void bgemm_kernel(
        const unsigned short* __restrict__ A,   // [M,K] bf16
        const unsigned short* __restrict__ Bt,  // [N,K] bf16
        unsigned short* __restrict__ C,         // [M,N] bf16
        int M, int N_, int K) {
    __shared__ unsigned short As[128 * 32];
    __shared__ unsigned short Bs[128 * 32];
    const int t = threadIdx.x;
    const int lane = t & 63;
    const int wave = t >> 6;
    const int row0 = blockIdx.y * 128, col0 = blockIdx.x * 128;
    const int wr = (wave >> 1) * 64, wc = (wave & 1) * 64;
    float4v acc[4][4] = {};
    for (int k0 = 0; k0 < K; k0 += 32) {
        #pragma unroll
        for (int c = 0; c < 2; ++c) {
            int i = c * 256 + t;
            int gr = row0 + (i >> 2); if (gr >= M) gr = M - 1;
            const unsigned short* gp = A + (size_t)gr * K + k0 + ((i & 3) << 3);
            __builtin_amdgcn_global_load_lds(
                (const __attribute__((address_space(1))) unsigned int*)gp,
                (__attribute__((address_space(3))) unsigned int*)&As[i * 8], 16, 0, 0);
        }
        #pragma unroll
        for (int c = 0; c < 2; ++c) {
            int i = c * 256 + t;
            int gn = col0 + (i >> 2);
            const unsigned short* gp = Bt + (size_t)gn * K + k0 + ((i & 3) << 3);
            __builtin_amdgcn_global_load_lds(
                (const __attribute__((address_space(1))) unsigned int*)gp,
                (__attribute__((address_space(3))) unsigned int*)&Bs[i * 8], 16, 0, 0);
        }
        __syncthreads();
        short8 af[4], bfr[4];
        #pragma unroll
        for (int i = 0; i < 4; ++i)
            af[i] = *(const short8*)&As[(wr + i * 16 + (lane & 15)) * 32 + (lane >> 4) * 8];
        #pragma unroll
        for (int j = 0; j < 4; ++j)
            bfr[j] = *(const short8*)&Bs[(wc + j * 16 + (lane & 15)) * 32 + (lane >> 4) * 8];
        #pragma unroll
        for (int i = 0; i < 4; ++i)
            #pragma unroll
            for (int j = 0; j < 4; ++j)
                acc[i][j] = __builtin_amdgcn_mfma_f32_16x16x32_bf16(af[i], bfr[j], acc[i][j], 0, 0, 0);
        __syncthreads();
    }
    #pragma unroll
    for (int i = 0; i < 4; ++i) {
        int rbase = row0 + wr + i * 16 + (lane >> 4) * 4;
        #pragma unroll
        for (int j = 0; j < 4; ++j) {
            int cc = col0 + wc + j * 16 + (lane & 15);
            #pragma unroll
            for (int p = 0; p < 4; ++p) {
                int r = rbase + p;
                if (r < M) C[(size_t)r * N_ + cc] = f2bf(acc[i][j][p]);
            }
        }
    }
}

// ---------------- attention scalars (bf16 inputs) ----------------
__global__ __launch_bounds__(256) void att1_kernel(const unsigned short* __restrict__ h1b,
                                                   const float* __restrict__ att_src,
                                                   const float* __restrict__ att_dst,
                                                   float* __restrict__ as1,
                                                   float* __restrict__ ad1, int N) {
    int wave = threadIdx.x >> 6, lane = threadIdx.x & 63;
    int node = blockIdx.x * 4 + wave;
    if (node >= N) return;
    int c0 = lane * 8;
    int4 r = *(const int4*)&h1b[(size_t)node * 512 + c0];
    float f0 = bflo(r.x), f1 = bfhi(r.x), f2 = bflo(r.y), f3 = bfhi(r.y);
    float f4 = bflo(r.z), f5 = bfhi(r.z), f6 = bflo(r.w), f7 = bfhi(r.w);
    float4 sA = *(const float4*)&att_src[c0], sB = *(const float4*)&att_src[c0 + 4];
    float4 dA = *(const float4*)&att_dst[c0], dB = *(const float4*)&att_dst[c0 + 4];
    float s = f0 * sA.x + f1 * sA.y + f2 * sA.z + f3 * sA.w
            + f4 * sB.x + f5 * sB.y + f6 * sB.z + f7 * sB.w;
    float d = f0 * dA.x + f1 * dA.y + f2 * dA.z + f3 * dA.w
            + f4 * dB.x + f5 * dB.y + f6 * dB.z + f7 * dB.w;
    #pragma unroll
    for (int o = 1; o <= 8; o <<= 1) { s += __shfl_xor(s, o); d += __shfl_xor(d, o); }
    if ((lane & 15) == 0) {
        int hd = lane >> 4;
        as1[node * 4 + hd] = s;
        ad1[node * 4 + hd] = d;
    }
}

__global__ __launch_bounds__(256) void att2_kernel(const unsigned short* __restrict__ h2b,
                                                   const float* __restrict__ att_src,
                                                   const float* __restrict__ att_dst,
                                                   float* __restrict__ as2,
                                                   float* __restrict__ ad2, int N) {
    int wave = threadIdx.x >> 6, lane = threadIdx.x & 63;
    int node = blockIdx.x * 4 + wave;
    if (node >= N) return;
    int c0 = lane * 4;
    int2 r = *(const int2*)&h2b[(size_t)node * 256 + c0];
    float f0 = bflo(r.x), f1 = bfhi(r.x), f2 = bflo(r.y), f3 = bfhi(r.y);
    float4 sv = *(const float4*)&att_src[c0];
    float4 dv = *(const float4*)&att_dst[c0];
    float s = f0 * sv.x + f1 * sv.y + f2 * sv.z + f3 * sv.w;
    float d = f0 * dv.x + f1 * dv.y + f2 * dv.z + f3 * dv.w;
    #pragma unroll
    for (int o = 32; o > 0; o >>= 1) { s += __shfl_xor(s, o); d += __shfl_xor(d, o); }
    if (lane == 0) { as2[node] = s; ad2[node] = d; }
}

// ---------------- edge-parallel attention-weight precompute ----------------
__global__ void wcalc1_kernel(const float4* __restrict__ as14, const float4* __restrict__ ad14,
                              const int* __restrict__ esrc, const int* __restrict__ edst,
                              float4* __restrict__ wexp4, int tot) {
    int e = blockIdx.x * blockDim.x + threadIdx.x;
    if (e >= tot) return;
    float4 a = as14[esrc[e]];
    float4 b = ad14[edst[e]];
    float4 w;
    w.x = __expf(lrelu(a.x + b.x));
    w.y = __expf(lrelu(a.y + b.y));
    w.z = __expf(lrelu(a.z + b.z));
    w.w = __expf(lrelu(a.w + b.w));
    wexp4[e] = w;
}

__global__ void wcalc2_kernel(const float* __restrict__ as2, const float* __restrict__ ad2,
                              const int* __restrict__ esrc, const int* __restrict__ edst,
                              float* __restrict__ wexp, int tot) {
    int e = blockIdx.x * blockDim.x + threadIdx.x;
    if (e >= tot) return;
    wexp[e] = __expf(lrelu(as2[esrc[e]] + ad2[edst[e]]));
}

// ---------------- edge aggregate (channel-split: 2 waves per node) ----------------
// Layer 1: wave covers 256 of the 512 channels (4 ch/lane, int2 gathers), unroll 8.
__global__ __launch_bounds__(256) void edge_agg1_kernel(
        const unsigned short* __restrict__ h1b,   // [N,512] bf16
        const float4* __restrict__ as14,
        const float4* __restrict__ ad14,
        const int* __restrict__ ofs,
        const int* __restrict__ esrc,
        const float* __restrict__ wexp,           // [tot*4]
        const float* __restrict__ b1,
        unsigned short* __restrict__ ho1b, int N) {
    int wid = threadIdx.x >> 6, lane = threadIdx.x & 63;
    int node = blockIdx.x * 2 + (wid >> 1);
    int half = wid & 1;
    if (node >= N) return;
    int beg = ofs[node], end = ofs[node + 1];
    float4 asn = as14[node], adn = ad14[node];
    float w0 = __expf(lrelu(asn.x + adn.x));
    float w1 = __expf(lrelu(asn.y + adn.y));
    float w2 = __expf(lrelu(asn.z + adn.z));
    float w3 = __expf(lrelu(asn.w + adn.w));
    float d0 = 0.f, d1 = 0.f, d2 = 0.f, d3 = 0.f;
    for (int e = beg + lane; e < end; e += 64) {
        float4 w = ((const float4*)wexp)[e];
        d0 += w.x; d1 += w.y; d2 += w.z; d3 += w.w;
    }
    #pragma unroll
    for (int o = 32; o > 0; o >>= 1) {
        d0 += __shfl_xor(d0, o); d1 += __shfl_xor(d1, o);
        d2 += __shfl_xor(d2, o); d3 += __shfl_xor(d3, o);
    }
    d0 += w0; d1 += w1; d2 += w2; d3 += w3;
    int hd = (half << 1) | (lane >> 5);           // head of this lane's channels
    int c0 = half * 256 + lane * 4;               // 4 channels per lane
    float wsh = hd == 0 ? w0 : hd == 1 ? w1 : hd == 2 ? w2 : w3;
    float dh  = hd == 0 ? d0 : hd == 1 ? d1 : hd == 2 ? d2 : d3;

    float acc[4];
    {
        int2 r = *(const int2*)&h1b[(size_t)node * 512 + c0];
        acc[0] = wsh * bflo(r.x); acc[1] = wsh * bfhi(r.x);
        acc[2] = wsh * bflo(r.y); acc[3] = wsh * bfhi(r.y);
    }
    int e = beg;
    for (; e + 8 <= end; e += 8) {
        int s[8]; float u[8]; int2 r[8];
        #pragma unroll
        for (int q = 0; q < 8; ++q) s[q] = esrc[e + q];
        #pragma unroll
        for (int q = 0; q < 8; ++q) u[q] = wexp[(size_t)(e + q) * 4 + hd];
        #pragma unroll
        for (int q = 0; q < 8; ++q) r[q] = *(const int2*)&h1b[(size_t)s[q] * 512 + c0];
        #pragma unroll
        for (int q = 0; q < 8; ++q) {
            acc[0] += u[q] * bflo(r[q].x); acc[1] += u[q] * bfhi(r[q].x);
            acc[2] += u[q] * bflo(r[q].y); acc[3] += u[q] * bfhi(r[q].y);
        }
    }
    for (; e < end; ++e) {
        int s = esrc[e];
        float u = wexp[(size_t)e * 4 + hd];
        int2 r = *(const int2*)&h1b[(size_t)s * 512 + c0];
        acc[0] += u * bflo(r.x); acc[1] += u * bfhi(r.x);
        acc[2] += u * bflo(r.y); acc[3] += u * bfhi(r.y);
    }
    float inv = 1.f / dh;
    float4 bv = *(const float4*)&b1[c0];
    float v0 = fmaxf(acc[0] * inv + bv.x, 0.f), v1 = fmaxf(acc[1] * inv + bv.y, 0.f);
    float v2 = fmaxf(acc[2] * inv + bv.z, 0.f), v3 = fmaxf(acc[3] * inv + bv.w, 0.f);
    int2 o;
    o.x = (int)((unsigned)f2bf(v0) | ((unsigned)f2bf(v1) << 16));
    o.y = (int)((unsigned)f2bf(v2) | ((unsigned)f2bf(v3) << 16));
    *(int2*)&ho1b[(size_t)node * 512 + c0] = o;
}

// Layer 2: wave covers 128 of the 256 channels (2 ch/lane, dword gathers), unroll 8.
__global__ __launch_bounds__(256) void edge_agg2_kernel(
        const unsigned short* __restrict__ h2b,   // [N,256] bf16
        const float* __restrict__ as2,
        const float* __restrict__ ad2,
        const int* __restrict__ ofs,
        const int* __restrict__ esrc,
        const float* __restrict__ wexp,           // [tot]
        const float* __restrict__ b2,
        float* __restrict__ ho2, int N) {
    int wid = threadIdx.x >> 6, lane = threadIdx.x & 63;
    int node = blockIdx.x * 2 + (wid >> 1);
    int half = wid & 1;
    if (node >= N) return;
    int beg = ofs[node], end = ofs[node + 1];
    float wself = __expf(lrelu(as2[node] + ad2[node]));
    float dsum = 0.f;
    for (int e = beg + lane; e < end; e += 64) dsum += wexp[e];
    #pragma unroll
    for (int o = 32; o > 0; o >>= 1) dsum += __shfl_xor(dsum, o);
    dsum += wself;
    int c0 = half * 128 + lane * 2;
    float a0, a1;
    {
        int r = *(const int*)&h2b[(size_t)node * 256 + c0];
        a0 = wself * bflo(r); a1 = wself * bfhi(r);
    }
    int e = beg;
    for (; e + 8 <= end; e += 8) {
        int s[8]; float u[8]; int r[8];
        #pragma unroll
        for (int q = 0; q < 8; ++q) s[q] = esrc[e + q];
        #pragma unroll
        for (int q = 0; q < 8; ++q) u[q] = wexp[e + q];
        #pragma unroll
        for (int q = 0; q < 8; ++q) r[q] = *(const int*)&h2b[(size_t)s[q] * 256 + c0];
        #pragma unroll
        for (int q = 0; q < 8; ++q) { a0 += u[q] * bflo(r[q]); a1 += u[q] * bfhi(r[q]); }
    }
    for (; e < end; ++e) {
        int s = esrc[e];
        float u = wexp[e];
        int r = *(const int*)&h2b[(size_t)s * 256 + c0];
        a0 += u * bflo(r); a1 += u * bfhi(r);
    }
    float inv = 1.f / dsum;
    float2 bv = *(const float2*)&b2[c0];
    float2 o;
    o.x = a0 * inv + bv.x; o.y = a1 * inv + bv.y;
    *(float2*)&ho2[(size_t)node * 256 + c0] = o;
}

// ---------------- global max pool, stage 1 (batch is sorted) ----------------
__global__ __launch_bounds__(256) void pool1_kernel(const float* __restrict__ ho2,
                                                    const int* __restrict__ batch,
                                                    int N, float* __restrict__ part) {
    int g = blockIdx.x, c = blockIdx.y, t = threadIdx.x;
    int lo = 0, hi = N;
    while (lo < hi) { int mid = (lo + hi) >> 1; if (batch[mid] < g) lo = mid + 1; else hi = mid; }
    int start = lo;
    lo = 0; hi = N;
    while (lo < hi) { int mid = (lo + hi) >> 1; if (batch[mid] < g + 1) lo = mid + 1; else hi = mid; }
    int end = lo;
    int len = end - start;
    int cb = start + (int)(((long long)len * c) / PCHUNK);
    int ce = start + (int)(((long long)len * (c + 1)) / PCHUNK);
    float m = -INFINITY;
    for (int n = cb; n < ce; ++n) m = fmaxf(m, ho2[(size_t)n * 256 + t]);
    part[((size_t)g * PCHUNK + c) * 256 + t] = m;
}

// ---------------- FC head (+pool stage 2) + log_softmax ----------------
__global__ __launch_bounds__(64) void head_kernel(const float* __restrict__ part,
                                                  const float* __restrict__ fc1w,
                                                  const float* __restrict__ fc1b,
                                                  const float* __restrict__ fc2w,
                                                  const float* __restrict__ fc2b,
                                                  float* __restrict__ out) {
    __shared__ float gr[256];
    __shared__ float hid[64];
    __shared__ float o10[NCLS];
    int g = blockIdx.x, t = threadIdx.x;
    for (int i = t; i < 256; i += 64) {
        float m = -INFINITY;
        #pragma unroll
        for (int c = 0; c < PCHUNK; ++c)
            m = fmaxf(m, part[((size_t)g * PCHUNK + c) * 256 + i]);
        gr[i] = m;
    }
    __syncthreads();
    float s = fc1b[t];
    for (int k = 0; k < 256; ++k) s += gr[k] * fc1w[k * 64 + t];
    hid[t] = s > 0.f ? s : 0.f;
    __syncthreads();
    if (t < NCLS) {
        float s2 = fc2b[t];
        for (int k = 0; k < 64; ++k) s2 += hid[k] * fc2w[k * NCLS + t];
        o10[t] = s2;
    }
    __syncthreads();
    if (t == 0) {
        float mx = -INFINITY;
        for (int c = 0; c < NCLS; ++c) mx = fmaxf(mx, o10[c]);
        float se = 0.f;
        for (int c = 0; c < NCLS; ++c) se += __expf(o10[c] - mx);
        float lse = mx + logf(se);
        for (int c = 0; c < NCLS; ++c) out[g * NCLS + c] = o10[c] - lse;
    }
}

extern "C" void kernel_launch(void* const* d_in, const int* in_sizes, int n_in,
                              void* d_out, int out_size, void* d_ws, size_t ws_size,
                              hipStream_t stream) {
    (void)n_in; (void)out_size; (void)ws_size;
    const float* x        = (const float*)d_in[0];
    const int*   ei       = (const int*)d_in[1];
    const int*   batch    = (const int*)d_in[2];
    const float* W1       = (const float*)d_in[3];
    const float* att_src1 = (const float*)d_in[4];
    const float* att_dst1 = (const float*)d_in[5];
    const float* b1       = (const float*)d_in[6];
    const float* W2       = (const float*)d_in[7];
    const float* att_src2 = (const float*)d_in[8];
    const float* att_dst2 = (const float*)d_in[9];
    const float* b2       = (const float*)d_in[10];
    const float* fc1w     = (const float*)d_in[11];
    const float* fc1b     = (const float*)d_in[12];
    const float* fc2w     = (const float*)d_in[13];
    const float* fc2b     = (const float*)d_in[14];

    const int N = in_sizes[2];
    const int E = in_sizes[1] / 2;
    const int tot = 2 * E;

    char* base = (char*)d_ws;
    size_t off = 0;
    auto alloc = [&](size_t bytes) -> void* {
        void* p = base + off;
        off = (off + bytes + 255) & ~(size_t)255;
        return p;
    };
    int*   ofs    = (int*)alloc((size_t)(N + 1) * 4);
    int*   cursor = (int*)alloc((size_t)N * 4);
    int*   esrc   = (int*)alloc((size_t)tot * 4);
    int*   edst   = (int*)alloc((size_t)tot * 4);
    float* as1    = (float*)alloc((size_t)N * HEADS * 4);
    float* ad1    = (float*)alloc((size_t)N * HEADS * 4);
    float* as2    = (float*)alloc((size_t)N * 4);
    float* ad2    = (float*)alloc((size_t)N * 4);
    float* wexp1  = (float*)alloc((size_t)tot * HEADS * 4);
    float* wexp2  = (float*)alloc((size_t)tot * 4);
    unsigned short* xb   = (unsigned short*)alloc((size_t)N * FDIM * 2);
    unsigned short* W1t  = (unsigned short*)alloc((size_t)512 * 128 * 2);
    unsigned short* W2t  = (unsigned short*)alloc((size_t)256 * 512 * 2);
    unsigned short* h1b  = (unsigned short*)alloc((size_t)N * 512 * 2);
    unsigned short* ho1b = (unsigned short*)alloc((size_t)N * 512 * 2);
    unsigned short* h2b  = (unsigned short*)alloc((size_t)N * 256 * 2);
    float* ho2    = (float*)alloc((size_t)N * 256 * 4);
    float* ppart  = (float*)alloc((size_t)NGRAPH * PCHUNK * 256 * 4);

    // CSR build
    hipMemsetAsync(cursor, 0, (size_t)N * 4, stream);
    hist_kernel<<<(tot + 255) / 256, 256, 0, stream>>>(ei, E, cursor);
    scan_kernel<<<1, 1024, 0, stream>>>(cursor, ofs, N);
    scatter_kernel<<<(tot + 255) / 256, 256, 0, stream>>>(ei, E, cursor, esrc, edst);

    // bf16 conversions
    cvt_kernel<<<(N * FDIM / 4 + 255) / 256, 256, 0, stream>>>(x, xb, N * FDIM / 4);
    tconv_kernel<<<dim3(512 / 32, 128 / 32), dim3(32, 8), 0, stream>>>(W1, W1t, 128, 512);
    tconv_kernel<<<dim3(256 / 32, 512 / 32), dim3(32, 8), 0, stream>>>(W2, W2t, 512, 256);

    // Layer 1: h1 = x @ W1  (M=N, N=512, K=128)
    bgemm_kernel<<<dim3(512 / 128, (N + 127) / 128), 256, 0, stream>>>(xb, W1t, h1b, N, 512, 128);
    att1_kernel<<<(N + 3) / 4, 256, 0, stream>>>(h1b, att_src1, att_dst1, as1, ad1, N);
    wcalc1_kernel<<<(tot + 255) / 256, 256, 0, stream>>>((const float4*)as1, (const float4*)ad1,
                                                         esrc, edst, (float4*)wexp1, tot);
    edge_agg1_kernel<<<(N + 1) / 2, 256, 0, stream>>>(h1b, (const float4*)as1, (const float4*)ad1,
                                                      ofs, esrc, wexp1, b1, ho1b, N);

    // Layer 2: h2 = ho1 @ W2  (M=N, N=256, K=512)
    bgemm_kernel<<<dim3(256 / 128, (N + 127) / 128), 256, 0, stream>>>(ho1b, W2t, h2b, N, 256, 512);
    att2_kernel<<<(N + 3) / 4, 256, 0, stream>>>(h2b, att_src2, att_dst2, as2, ad2, N);
    wcalc2_kernel<<<(tot + 255) / 256, 256, 0, stream>>>(as2, ad2, esrc, edst, wexp2, tot);
    edge_agg2_kernel<<<(N + 1) / 2, 256, 0, stream>>>(h2b, as2, ad2, ofs, esrc, wexp2, b2, ho2, N);

    // Pool stage 1 + fused (pool stage 2 + head)
    pool1_kernel<<<dim3(NGRAPH, PCHUNK), 256, 0, stream>>>(ho2, batch, N, ppart);
    head_kernel<<<NGRAPH, 64, 0, stream>>>(ppart, fc1w, fc1b, fc2w, fc2b, (float*)d_out);
}